// Round 4
// baseline (205.294 us; speedup 1.0000x reference)
//
#include <hip/hip_runtime.h>
#include <math.h>

#define B_  2
#define Q_  2048
#define CQ_ 512
#define H_  8
#define D_  64
#define M_  (B_*Q_)   // 4096
#define L2E 1.44269504088896f

typedef __bf16 bf16;
typedef __bf16 bf16x4 __attribute__((ext_vector_type(4)));
typedef __bf16 bf16x8 __attribute__((ext_vector_type(8)));
typedef float  f32x4  __attribute__((ext_vector_type(4)));

// async global->LDS, 16 bytes per lane; lds dest = wave-uniform base + lane*16
__device__ __forceinline__ void gl_lds16(const bf16* g, bf16* l) {
    __builtin_amdgcn_global_load_lds(
        (const __attribute__((address_space(1))) unsigned int*)g,
        (__attribute__((address_space(3))) unsigned int*)l, 16, 0, 0);
}

// ---------------------------------------------------------------------------
// fp32 -> bf16 conversion: q_x -> qxb, w_qkv+w_g -> wcat (concat rows), w_o -> wob
// ---------------------------------------------------------------------------
#define S0 (4096*512)    // q_x
#define S1 (1536*512)    // w_qkv
#define S2 (512*512)     // w_g
#define S3 (512*512)     // w_o
__global__ __launch_bounds__(256)
void convert_kernel(const float* __restrict__ qx, const float* __restrict__ wqkv,
                    const float* __restrict__ wg, const float* __restrict__ wo,
                    bf16* __restrict__ qxb, bf16* __restrict__ wcat, bf16* __restrict__ wob)
{
    const long long t = (long long)blockIdx.x * 256 + threadIdx.x;
    const long long e = t * 8;
    const float* src; bf16* dst;
    if (e < S0)                { src = qx + e;                  dst = qxb + e; }
    else if (e < S0 + S1)      { src = wqkv + (e - S0);         dst = wcat + (e - S0); }
    else if (e < S0 + S1 + S2) { src = wg + (e - S0 - S1);      dst = wcat + S1 + (e - S0 - S1); }
    else                       { src = wo + (e - S0 - S1 - S2); dst = wob + (e - S0 - S1 - S2); }
    const float4 a = *(const float4*)(src);
    const float4 b = *(const float4*)(src + 4);
    bf16x8 v;
    v[0] = (bf16)a.x; v[1] = (bf16)a.y; v[2] = (bf16)a.z; v[3] = (bf16)a.w;
    v[4] = (bf16)b.x; v[5] = (bf16)b.y; v[6] = (bf16)b.z; v[7] = (bf16)b.w;
    *(bf16x8*)dst = v;
}

// ---------------------------------------------------------------------------
// bf16 MFMA GEMM: C[M,N] = A[M,512] * W[N,512]^T, K=512, BK=32.
// Block 256 = 4 waves in 2x2; wave tile (BM/2)x(BN/2); 16x16x32 MFMA.
// EPI 0: n<512 -> q (scaled by log2e/8, [B,H,Q,D]); <1024 -> k (FRAGMENT order);
//        <1536 -> v (FRAGMENT order); else gate: sigmoid(c+b_g) -> gb bf16 [M,512]
// EPI 1: out[m*512+n] = c + b_o[n]  (fp32)
// K frag order (per bh): off = rg*1024 + c*128 + l*8 + j   (rg=kk>>4,l=kk&15,c=d>>3,j=d&7)
// V frag order (per bh): off = tile*4096 + dt*1024 + kc*128 + dl*8 + j
//                        (tile=kk>>6, kc=(kk&63)>>3, j=kk&7, dt=d>>4, dl=d&15)
// ---------------------------------------------------------------------------
template<int BM, int BN, int EPI>
__global__ __launch_bounds__(256)
void gemm_bf16(const bf16* __restrict__ A, const bf16* __restrict__ W,
               const float* __restrict__ bvec, float* __restrict__ fout,
               bf16* __restrict__ qb, bf16* __restrict__ kb, bf16* __restrict__ vb,
               bf16* __restrict__ gb)
{
    constexpr int MI = BM / 32, NJ = BN / 32;
    __shared__ __align__(16) bf16 As[BM * 32];
    __shared__ __align__(16) bf16 Bs[BN * 32];

    const int t = threadIdx.x;
    const int w = t >> 6, lane = t & 63;
    const int l15 = lane & 15, quad = lane >> 4;
    const int wm = w & 1, wn = w >> 1;
    const int bm = blockIdx.x * BM;
    const int bn = blockIdx.y * BN;

    f32x4 acc[MI][NJ] = {};

    const int rr = t >> 2;
    const int cc = (t & 3) * 8;

    for (int k0 = 0; k0 < 512; k0 += 32) {
        #pragma unroll
        for (int i = 0; i < BM / 64; ++i)
            gl_lds16(A + (size_t)(bm + i * 64 + rr) * 512 + k0 + cc,
                     As + (i * 64 + w * 16) * 32);
        #pragma unroll
        for (int i = 0; i < BN / 64; ++i)
            gl_lds16(W + (size_t)(bn + i * 64 + rr) * 512 + k0 + cc,
                     Bs + (i * 64 + w * 16) * 32);
        __asm__ volatile("s_waitcnt vmcnt(0)" ::: "memory");
        __syncthreads();

        bf16x8 af[MI], bfr[NJ];
        #pragma unroll
        for (int i = 0; i < MI; ++i)
            af[i] = *(const bf16x8*)(As + (wm * (BM / 2) + i * 16 + l15) * 32 + quad * 8);
        #pragma unroll
        for (int j = 0; j < NJ; ++j)
            bfr[j] = *(const bf16x8*)(Bs + (wn * (BN / 2) + j * 16 + l15) * 32 + quad * 8);
        #pragma unroll
        for (int i = 0; i < MI; ++i)
            #pragma unroll
            for (int j = 0; j < NJ; ++j)
                acc[i][j] = __builtin_amdgcn_mfma_f32_16x16x32_bf16(af[i], bfr[j], acc[i][j], 0, 0, 0);
        __syncthreads();
    }

    #pragma unroll
    for (int i = 0; i < MI; ++i) {
        #pragma unroll
        for (int r = 0; r < 4; ++r) {
            const int m = bm + wm * (BM / 2) + i * 16 + quad * 4 + r;
            const int b = m >> 11, qq = m & 2047;
            #pragma unroll
            for (int j = 0; j < NJ; ++j) {
                const int n = bn + wn * (BN / 2) + j * 16 + l15;
                const float cval = acc[i][j][r];
                if constexpr (EPI == 0) {
                    const int part = n >> 9;
                    const int h = (n >> 6) & 7, d = n & 63;
                    const size_t bhbase = (size_t)(b * H_ + h) * (Q_ * D_);
                    if (part == 0) {
                        qb[bhbase + (size_t)qq * D_ + d] = (bf16)(cval * (0.125f * L2E));
                    } else if (part == 1) {
                        const int rg = qq >> 4, ll = qq & 15, ch = d >> 3, jj = d & 7;
                        kb[bhbase + rg * 1024 + ch * 128 + ll * 8 + jj] = (bf16)cval;
                    } else if (part == 2) {
                        const int tile = qq >> 6, kc2 = (qq & 63) >> 3, jj = qq & 7;
                        const int dt = d >> 4, dl = d & 15;
                        vb[bhbase + tile * 4096 + dt * 1024 + kc2 * 128 + dl * 8 + jj] = (bf16)cval;
                    } else {
                        const int gcol = n & 511;
                        const float x = cval + bvec[gcol];
                        gb[(size_t)m * 512 + gcol] = (bf16)(1.f / (1.f + __expf(-x)));
                    }
                } else {
                    fout[(size_t)m * 512 + n] = cval + bvec[n];
                }
            }
        }
    }
}

// ---------------------------------------------------------------------------
// Barrier-free MFMA flash attention, transposed dataflow.
// Wave = 16 q-rows of one (b,h); lane's q-row = q0 + wv*16 + l15.
// K and V are read DIRECTLY from global in MFMA-fragment order (1 KB coalesced
// loads, L2-resident: 512 KB per head, <=1 MB per XCD). LDS holds only the
// per-wave 16x72 P transpose; no __syncthreads anywhere.
// Softmax in exp2 domain (q pre-scaled by log2e/8; bias folded via fma).
// Next-tile K/V/bias register prefetch hides L2 latency.
// ---------------------------------------------------------------------------
__global__ __launch_bounds__(256, 2)
void attn_kernel(const bf16* __restrict__ qb, const bf16* __restrict__ kf,
                 const bf16* __restrict__ vf, const float* __restrict__ bias,
                 const bf16* __restrict__ g, bf16* __restrict__ og)
{
    __shared__ __align__(16) bf16 Ps[4][16 * 72];

    const int tid  = threadIdx.x;
    const int wv   = tid >> 6, lane = tid & 63;
    const int l15  = lane & 15, quad = lane >> 4;
    const int x    = blockIdx.x;
    const int bh   = ((x & 1) << 3) | (x >> 1);  // XCD gets one b, two h's -> bias L2 reuse
    const int b    = bh >> 3, h = bh & 7;
    const int qrow = blockIdx.y * 64 + wv * 16 + l15;

    const bf16* qptr = qb + ((size_t)bh * Q_ + qrow) * D_;
    const bf16x8 bq0 = *(const bf16x8*)(qptr + quad * 8);
    const bf16x8 bq1 = *(const bf16x8*)(qptr + 32 + quad * 8);

    f32x4 acc[4] = {};                       // O^T: acc[dt][r] = O[qrow][dt*16+quad*4+r]
    float m_run = -INFINITY, l_run = 0.f;

    const bf16*  kfb  = kf + (size_t)bh * (Q_ * D_);
    const bf16*  vfb  = vf + (size_t)bh * (Q_ * D_);
    const float* brow = bias + ((size_t)b * Q_ + qrow) * Q_;

    bf16x8 kc[8], vc[8], kn[8], vn[8];
    float4 bc[4], bn4[4];

    // ---- prologue: tile 0 operand loads (all 1 KB coalesced) ----
    #pragma unroll
    for (int kt = 0; kt < 4; ++kt) {
        kc[kt * 2]     = *(const bf16x8*)(kfb + (kt * 8 + quad) * 128 + l15 * 8);
        kc[kt * 2 + 1] = *(const bf16x8*)(kfb + (kt * 8 + quad + 4) * 128 + l15 * 8);
        vc[kt * 2]     = *(const bf16x8*)(vfb + (kt * 8 + quad) * 128 + l15 * 8);
        vc[kt * 2 + 1] = *(const bf16x8*)(vfb + (kt * 8 + quad + 4) * 128 + l15 * 8);
        bc[kt] = *(const float4*)(brow + kt * 16 + quad * 4);
    }

    bf16* pw = Ps[wv] + l15 * 72;

    #pragma unroll 2
    for (int t = 0; t < 32; ++t) {
        // prefetch next tile's K/V/bias into registers
        if (t < 31) {
            const int off = (t + 1) * 4096;
            const int boff = (t + 1) * 64;
            #pragma unroll
            for (int kt = 0; kt < 4; ++kt) {
                kn[kt * 2]     = *(const bf16x8*)(kfb + off + (kt * 8 + quad) * 128 + l15 * 8);
                kn[kt * 2 + 1] = *(const bf16x8*)(kfb + off + (kt * 8 + quad + 4) * 128 + l15 * 8);
                vn[kt * 2]     = *(const bf16x8*)(vfb + off + (kt * 8 + quad) * 128 + l15 * 8);
                vn[kt * 2 + 1] = *(const bf16x8*)(vfb + off + (kt * 8 + quad + 4) * 128 + l15 * 8);
                bn4[kt] = *(const float4*)(brow + boff + kt * 16 + quad * 4);
            }
        }

        // ---- scores S^T (A=K, B=Q); bias folded with log2e via fma ----
        float sc[4][4];
        #pragma unroll
        for (int kt = 0; kt < 4; ++kt) {
            f32x4 sacc = {0.f, 0.f, 0.f, 0.f};
            sacc = __builtin_amdgcn_mfma_f32_16x16x32_bf16(kc[kt * 2],     bq0, sacc, 0, 0, 0);
            sacc = __builtin_amdgcn_mfma_f32_16x16x32_bf16(kc[kt * 2 + 1], bq1, sacc, 0, 0, 0);
            sc[kt][0] = fmaf(bc[kt].x, L2E, sacc[0]);
            sc[kt][1] = fmaf(bc[kt].y, L2E, sacc[1]);
            sc[kt][2] = fmaf(bc[kt].z, L2E, sacc[2]);
            sc[kt][3] = fmaf(bc[kt].w, L2E, sacc[3]);
        }

        // ---- online softmax (exp2 domain), 2 shuffles per reduction ----
        float tmax = -INFINITY;
        #pragma unroll
        for (int kt = 0; kt < 4; ++kt)
            tmax = fmaxf(tmax, fmaxf(fmaxf(sc[kt][0], sc[kt][1]),
                                     fmaxf(sc[kt][2], sc[kt][3])));
        tmax = fmaxf(tmax, __shfl_xor(tmax, 16, 64));
        tmax = fmaxf(tmax, __shfl_xor(tmax, 32, 64));

        const float mn = fmaxf(m_run, tmax);
        const float alpha = __builtin_amdgcn_exp2f(m_run - mn);
        m_run = mn;

        float rsum = 0.f;
        #pragma unroll
        for (int kt = 0; kt < 4; ++kt)
            #pragma unroll
            for (int r = 0; r < 4; ++r) {
                sc[kt][r] = __builtin_amdgcn_exp2f(sc[kt][r] - mn);
                rsum += sc[kt][r];
            }
        rsum += __shfl_xor(rsum, 16, 64);
        rsum += __shfl_xor(rsum, 32, 64);
        l_run = l_run * alpha + rsum;
        #pragma unroll
        for (int dt = 0; dt < 4; ++dt) acc[dt] *= alpha;

        // ---- P^T -> per-wave LDS [qrow][key] (4x b64) ----
        #pragma unroll
        for (int kt = 0; kt < 4; ++kt) {
            bf16x4 p4;
            p4[0] = (bf16)sc[kt][0]; p4[1] = (bf16)sc[kt][1];
            p4[2] = (bf16)sc[kt][2]; p4[3] = (bf16)sc[kt][3];
            *(bf16x4*)(pw + kt * 16 + quad * 4) = p4;
        }
        __asm__ volatile("s_waitcnt lgkmcnt(0)" ::: "memory");

        // ---- PV: O^T += V^T * P^T ----
        #pragma unroll
        for (int kt2 = 0; kt2 < 2; ++kt2) {
            const bf16x8 bp = *(const bf16x8*)(pw + kt2 * 32 + quad * 8);
            #pragma unroll
            for (int dt = 0; dt < 4; ++dt)
                acc[dt] = __builtin_amdgcn_mfma_f32_16x16x32_bf16(vc[dt * 2 + kt2], bp, acc[dt], 0, 0, 0);
        }

        // ---- rotate prefetch registers ----
        if (t < 31) {
            #pragma unroll
            for (int i = 0; i < 8; ++i) { kc[i] = kn[i]; vc[i] = vn[i]; }
            #pragma unroll
            for (int kt = 0; kt < 4; ++kt) bc[kt] = bn4[kt];
        }
    }

    // ---- normalize, gate, store bf16 ----
    const float inv = 1.f / l_run;
    const size_t obase = ((size_t)(b * Q_ + qrow)) * 512 + h * 64;
    #pragma unroll
    for (int dt = 0; dt < 4; ++dt) {
        const bf16x4 gv = *(const bf16x4*)(g + obase + dt * 16 + quad * 4);
        bf16x4 ov;
        #pragma unroll
        for (int r = 0; r < 4; ++r)
            ov[r] = (bf16)(acc[dt][r] * inv * (float)gv[r]);
        *(bf16x4*)(og + obase + dt * 16 + quad * 4) = ov;
    }
}

// ---------------------------------------------------------------------------
extern "C" void kernel_launch(void* const* d_in, const int* in_sizes, int n_in,
                              void* d_out, int out_size, void* d_ws, size_t ws_size,
                              hipStream_t stream)
{
    const float* q_x   = (const float*)d_in[0];
    const float* bias  = (const float*)d_in[2];
    const float* w_qkv = (const float*)d_in[3];
    const float* w_o   = (const float*)d_in[4];
    const float* b_o   = (const float*)d_in[5];
    const float* w_g   = (const float*)d_in[6];
    const float* b_g   = (const float*)d_in[7];
    float* out = (float*)d_out;

    char* ws = (char*)d_ws;
    bf16* qxb  = (bf16*)(ws);                    // 4 MB   [4096,512]
    bf16* wcat = (bf16*)(ws + (4u  << 20));      // 2 MB   [2048,512] = w_qkv ++ w_g
    bf16* wob  = (bf16*)(ws + (6u  << 20));      // 0.5 MB [512,512]
    bf16* qb   = (bf16*)(ws + (8u  << 20));      // 4 MB   [B,H,Q,D]
    bf16* kb   = (bf16*)(ws + (12u << 20));      // 4 MB   K fragment-ordered
    bf16* vb   = (bf16*)(ws + (16u << 20));      // 4 MB   V fragment-ordered
    bf16* gb   = (bf16*)(ws + (20u << 20));      // 4 MB   [4096,512]
    bf16* ogb  = (bf16*)(ws + (24u << 20));      // 4 MB   [4096,512]

    // 1) fp32 -> bf16 conversions
    convert_kernel<<<(S0 + S1 + S2 + S3) / (256 * 8), 256, 0, stream>>>(
        q_x, w_qkv, w_g, w_o, qxb, wcat, wob);
    // 2) fused QKV + gate projection (bf16 MFMA), N = 2048
    gemm_bf16<128, 128, 0><<<dim3(32, 16), 256, 0, stream>>>(
        qxb, wcat, b_g, nullptr, qb, kb, vb, gb);
    // 3) barrier-free MFMA flash attention + gating
    attn_kernel<<<dim3(B_ * H_, Q_ / 64), 256, 0, stream>>>(qb, kb, vb, bias, gb, ogb);
    // 4) output projection + b_o
    gemm_bf16<64, 128, 1><<<dim3(64, 4), 256, 0, stream>>>(
        ogb, wob, b_o, out, nullptr, nullptr, nullptr, nullptr);
}